// Round 16
// baseline (1762.509 us; speedup 1.0000x reference)
//
#include <hip/hip_runtime.h>
#include <cstdint>
#include <cstddef>

typedef unsigned short u16;
typedef __attribute__((ext_vector_type(8))) short short8;
typedef __attribute__((ext_vector_type(4))) float f32x4;

#define DEV __device__ __forceinline__

DEV float bf2f(u16 u) {
    union { float f; uint32_t i; } c; c.i = ((uint32_t)u) << 16; return c.f;
}
DEV u16 f2bf(float f) {
    union { float f; uint32_t i; } c; c.f = f;
    uint32_t r = c.i + 0x7FFF + ((c.i >> 16) & 1);
    return (u16)(r >> 16);
}

DEV void gload16(const void* g, void* l) {
    __builtin_amdgcn_global_load_lds(
        (const __attribute__((address_space(1))) void*)g,
        (__attribute__((address_space(3))) void*)l, 16, 0, 0);
}

template<int N> DEV void waitv() {
    if constexpr (N == 0)      asm volatile("s_waitcnt vmcnt(0)" ::: "memory");
    else if constexpr (N == 4) asm volatile("s_waitcnt vmcnt(4)" ::: "memory");
    else if constexpr (N == 8) asm volatile("s_waitcnt vmcnt(8)" ::: "memory");
    else                       asm volatile("s_waitcnt vmcnt(0)" ::: "memory");
}

// T1: bijective XCD-aware block swizzle (m204 form; all grids are %8==0).
// HW runs launch-index b on XCD b%8; remap so each XCD gets a CONTIGUOUS
// logical chunk -> panel-sharing neighbor blocks hit the same (private) L2.
DEV void xcd_swz(int& bx, int& by) {
    const int gx  = gridDim.x;
    const int nwg = gx * gridDim.y;
    const int lin = blockIdx.y * gx + blockIdx.x;
    const int q   = nwg >> 3;
    const int L   = (lin & 7) * q + (lin >> 3);
    bx = L % gx;
    by = L / gx;
}

// ---------------------------------------------------------------------------
// gemm256_blk: 256x256 tile, BK=32, 8 waves, NBUF=3, 2-sub-phase schedule,
// blocked [K/64][rows][64] operands (r13-validated coalesced staging).
// EPI 5: bf16 = acc+bias routed by col>>10 (QKV).
// EPI 6: bf16 = gelu(acc+bias) -> BLOCKED [col>>6][row][col&63] (FFN1).
// ---------------------------------------------------------------------------
template<int EPI>
__global__ __launch_bounds__(512)
void gemm256_blk(const u16* __restrict__ Ablk, const u16* __restrict__ Bblk,
                 void* __restrict__ C, const float* __restrict__ bias,
                 int K, int Mtot, int Ntot)
{
    constexpr int THREADS = 512;
    constexpr int BM = 256, BN = 256, BK = 32;
    constexpr int MR = 8, NR = 4;
    __shared__ __align__(16) u16 As[3 * BM * BK];
    __shared__ __align__(16) u16 Bs[3 * BN * BK];

    int bxs, bys; xcd_swz(bxs, bys);
    const int tid = threadIdx.x, lane = tid & 63, wid = tid >> 6;
    const int wr = wid >> 2, wc = wid & 3;
    const int lr = lane & 15, lk = lane >> 4;
    const int m0 = bxs * BM, n0 = bys * BN;
    const long planeA = (long)Mtot * 64, planeB = (long)Ntot * 64;

    f32x4 acc[MR][NR] = {};

    auto stageA = [&](int buf, int k0) {
        const long base = (long)(k0 >> 6) * planeA + (k0 & 32);
#pragma unroll
        for (int i = 0; i < 2; ++i) {
            int ch = i * THREADS + tid;
            int rp = ch >> 3, s = ch & 7, d = s ^ (rp & 7);
            const u16* g = Ablk + base + (long)(m0 + ((rp << 1) | (d & 1))) * 64 + ((d >> 1) << 3);
            gload16(g, (char*)As + (size_t)buf * (BM * BK * 2) + ch * 16);
        }
    };
    auto stageB = [&](int buf, int k0) {
        const long base = (long)(k0 >> 6) * planeB + (k0 & 32);
#pragma unroll
        for (int i = 0; i < 2; ++i) {
            int ch = i * THREADS + tid;
            int rp = ch >> 3, s = ch & 7, d = s ^ (rp & 7);
            const u16* g = Bblk + base + (long)(n0 + ((rp << 1) | (d & 1))) * 64 + ((d >> 1) << 3);
            gload16(g, (char*)Bs + (size_t)buf * (BN * BK * 2) + ch * 16);
        }
    };
    auto lds_off = [&](int row) -> int {
        int rp = row >> 1;
        int s  = ((lk << 1) | (row & 1)) ^ (rp & 7);
        return rp * 64 + s * 8;
    };

    const int nt = K >> 5;

    stageA(0, 0); stageB(0, 0);
    if (nt > 1) { stageA(1, BK); stageB(1, BK); }
    if (nt > 1) waitv<4>(); else waitv<0>();
    __builtin_amdgcn_s_barrier();

    for (int k = 0; k < nt; ++k) {
        const int cur = k % 3;
        const int nxt = (k + 2) % 3;
        const u16* Ac = As + (size_t)cur * (BM * BK);
        const u16* Bc = Bs + (size_t)cur * (BN * BK);
        short8 af[MR], bf[NR];

#pragma unroll
        for (int n = 0; n < NR; ++n)
            bf[n] = *(const short8*)(Bc + lds_off(wc * 64 + n * 16 + lr));
#pragma unroll
        for (int m = 0; m < 4; ++m)
            af[m] = *(const short8*)(Ac + lds_off(wr * 128 + m * 16 + lr));
        if (k + 2 < nt) stageA(nxt, (k + 2) * BK);
        asm volatile("s_waitcnt lgkmcnt(0)" ::: "memory");
        __builtin_amdgcn_s_setprio(1);
#pragma unroll
        for (int m = 0; m < 4; ++m)
#pragma unroll
            for (int n = 0; n < NR; ++n)
                acc[m][n] = __builtin_amdgcn_mfma_f32_16x16x32_bf16(af[m], bf[n], acc[m][n], 0, 0, 0);
        __builtin_amdgcn_s_setprio(0);

#pragma unroll
        for (int m = 4; m < 8; ++m)
            af[m] = *(const short8*)(Ac + lds_off(wr * 128 + m * 16 + lr));
        if (k + 2 < nt) stageB(nxt, (k + 2) * BK);
        asm volatile("s_waitcnt lgkmcnt(0)" ::: "memory");
        __builtin_amdgcn_s_setprio(1);
#pragma unroll
        for (int m = 4; m < 8; ++m)
#pragma unroll
            for (int n = 0; n < NR; ++n)
                acc[m][n] = __builtin_amdgcn_mfma_f32_16x16x32_bf16(af[m], bf[n], acc[m][n], 0, 0, 0);
        __builtin_amdgcn_s_setprio(0);

        if (k + 1 < nt) {
            if (k + 2 < nt) waitv<4>(); else waitv<0>();
            __builtin_amdgcn_s_barrier();
        }
    }

#pragma unroll
    for (int m = 0; m < MR; ++m) {
        const int rowb = m0 + wr * 128 + m * 16 + (lane >> 4) * 4;
#pragma unroll
        for (int n = 0; n < NR; ++n) {
            const int col = n0 + wc * 64 + n * 16 + lr;
            const float bv = bias[col];
#pragma unroll
            for (int j = 0; j < 4; ++j) {
                float v = acc[m][n][j];
                if (EPI == 6) {
                    float t = v + bv;
                    ((u16*)C)[(long)(col >> 6) * 262144L + (long)(rowb + j) * 64 + (col & 63)]
                        = f2bf(0.5f * t * (1.0f + erff(t * 0.70710678118654752f)));
                } else {  // EPI 5: QKV routing
                    const long qidx = (long)(col >> 10) * 4194304L
                                    + (long)(rowb + j) * 1024 + (col & 1023);
                    ((u16*)C)[qidx] = f2bf(v + bv);
                }
            }
        }
    }
}

// ---------------------------------------------------------------------------
// gemm_k64 (r13-proven): 128x128, BK=64, blocked A/B, for N=1024 GEMMs.
// EPI: f32 = acc + bias[col] + resid[row*1024+col].
// ---------------------------------------------------------------------------
__global__ __launch_bounds__(512)
void gemm_k64(const u16* __restrict__ Ablk, const u16* __restrict__ Bblk,
              float* __restrict__ C, const float* __restrict__ bias,
              const float* __restrict__ resid, int K, int Mtot, int Ntot)
{
    constexpr int THREADS = 512;
    constexpr int BM = 128, BN = 128;
    constexpr int MR = 4, NR = 2;
    __shared__ __align__(16) u16 As[3 * BM * 64];
    __shared__ __align__(16) u16 Bs[3 * BN * 64];

    int bxs, bys; xcd_swz(bxs, bys);
    const int tid = threadIdx.x, lane = tid & 63, wid = tid >> 6;
    const int wr = wid >> 2, wc = wid & 3;
    const int lr = lane & 15, lk = lane >> 4;
    const int m0 = bxs * BM, n0 = bys * BN;
    const long planeA = (long)Mtot * 64, planeB = (long)Ntot * 64;

    f32x4 acc[MR][NR] = {};

    auto stageA = [&](int buf, int k0) {
#pragma unroll
        for (int i = 0; i < 2; ++i) {
            int ch = i * THREADS + tid;
            int row = ch >> 3, s = ch & 7, d = s ^ (row & 7);
            const u16* g = Ablk + (long)(k0 >> 6) * planeA + (long)(m0 + row) * 64 + d * 8;
            gload16(g, (char*)As + (size_t)buf * (BM * 128) + ch * 16);
        }
    };
    auto stageB = [&](int buf, int k0) {
#pragma unroll
        for (int i = 0; i < 2; ++i) {
            int ch = i * THREADS + tid;
            int row = ch >> 3, s = ch & 7, d = s ^ (row & 7);
            const u16* g = Bblk + (long)(k0 >> 6) * planeB + (long)(n0 + row) * 64 + d * 8;
            gload16(g, (char*)Bs + (size_t)buf * (BN * 128) + ch * 16);
        }
    };
    auto lds_off = [&](int row, int ks) -> int {
        return row * 64 + ((ks ^ (row & 7)) << 3);
    };

    const int nt = K >> 6;

    stageA(0, 0); stageB(0, 0);
    if (nt > 1) { stageA(1, 64); stageB(1, 64); }
    if (nt > 2) { stageA(2, 128); stageB(2, 128); }
    if (nt > 2)      waitv<8>();
    else if (nt > 1) waitv<4>();
    else             waitv<0>();
    __builtin_amdgcn_s_barrier();

    for (int k = 0; k < nt; ++k) {
        const int cur = k % 3;
        const u16* Ac = As + (size_t)cur * (BM * 64);
        const u16* Bc = Bs + (size_t)cur * (BN * 64);
        short8 af[2][MR], bf[2][NR];
#pragma unroll
        for (int h = 0; h < 2; ++h) {
#pragma unroll
            for (int m = 0; m < MR; ++m)
                af[h][m] = *(const short8*)(Ac + lds_off(wr * 64 + m * 16 + lr, h * 4 + lk));
#pragma unroll
            for (int n = 0; n < NR; ++n)
                bf[h][n] = *(const short8*)(Bc + lds_off(wc * 32 + n * 16 + lr, h * 4 + lk));
        }

        asm volatile("s_waitcnt lgkmcnt(0)" ::: "memory");
        __builtin_amdgcn_s_barrier();

        if (k + 3 < nt) { stageA(cur, (k + 3) * 64); stageB(cur, (k + 3) * 64); }

        __builtin_amdgcn_s_setprio(1);
#pragma unroll
        for (int h = 0; h < 2; ++h)
#pragma unroll
            for (int m = 0; m < MR; ++m)
#pragma unroll
                for (int n = 0; n < NR; ++n)
                    acc[m][n] = __builtin_amdgcn_mfma_f32_16x16x32_bf16(af[h][m], bf[h][n], acc[m][n], 0, 0, 0);
        __builtin_amdgcn_s_setprio(0);

        if (k + 1 < nt) {
            if (k + 4 <= nt)      waitv<8>();
            else if (k + 3 == nt) waitv<4>();
            else                  waitv<0>();
            __builtin_amdgcn_s_barrier();
        }
    }

#pragma unroll
    for (int m = 0; m < MR; ++m) {
        const int rowb = m0 + wr * 64 + m * 16 + (lane >> 4) * 4;
#pragma unroll
        for (int n = 0; n < NR; ++n) {
            const int col = n0 + wc * 32 + n * 16 + lr;
            const float bv = bias[col];
#pragma unroll
            for (int j = 0; j < 4; ++j) {
                const long idx = (long)(rowb + j) * 1024 + col;
                C[idx] = acc[m][n][j] + bv + resid[idx];
            }
        }
    }
}

// ---------------------------------------------------------------------------
// Fused attention (r12-proven) + T1 swizzle so the 8 q-tile blocks of each
// (b,h) group land on ONE XCD (K/V panels localized in that L2).
// ---------------------------------------------------------------------------
__global__ __launch_bounds__(512)
void attn_kernel(const u16* __restrict__ Qb, const u16* __restrict__ Kb,
                 const u16* __restrict__ vt, const int* __restrict__ seq,
                 u16* __restrict__ ctxB)
{
    __shared__ __align__(16) u16 Ss[64 * 512];
    int bxs, bys; xcd_swz(bxs, bys);
    const int tid = threadIdx.x, lane = tid & 63, wid = tid >> 6;
    const int bh = bys;
    const int b  = bh >> 4;
    const int q0 = bxs << 6;
    const u16* Qh = Qb + ((long)bh << 15) + (long)q0 * 64;
    const u16* Kh = Kb + ((long)bh << 15);
    const u16* Vh = vt + ((long)bh << 15);
    const int lr = lane & 15, lk = lane >> 4;

    f32x4 sacc[4][4] = {};
    {
        short8 af[4], bf[4];
#pragma unroll
        for (int s = 0; s < 2; ++s) {
#pragma unroll
            for (int m = 0; m < 4; ++m)
                af[m] = *(const short8*)(Qh + (long)(m * 16 + lr) * 64 + s * 32 + lk * 8);
#pragma unroll
            for (int n = 0; n < 4; ++n)
                bf[n] = *(const short8*)(Kh + (long)(wid * 64 + n * 16 + lr) * 64 + s * 32 + lk * 8);
#pragma unroll
            for (int m = 0; m < 4; ++m)
#pragma unroll
                for (int n = 0; n < 4; ++n)
                    sacc[m][n] = __builtin_amdgcn_mfma_f32_16x16x32_bf16(af[m], bf[n], sacc[m][n], 0, 0, 0);
        }
    }
#pragma unroll
    for (int m = 0; m < 4; ++m) {
#pragma unroll
        for (int n = 0; n < 4; ++n) {
            const int k = wid * 64 + n * 16 + lr;
#pragma unroll
            for (int j = 0; j < 4; ++j) {
                const int q = m * 16 + (lane >> 4) * 4 + j;
                const int col = (((k >> 3) ^ (q & 7)) << 3) | (k & 7);
                Ss[q * 512 + col] = f2bf(sacc[m][n][j] * 0.125f);
            }
        }
    }
    __syncthreads();

    const int* sq = seq + (b << 9) + (lane << 3);
    int msk[8];
#pragma unroll
    for (int i = 0; i < 8; ++i) msk[i] = sq[i];
#pragma unroll
    for (int r = 0; r < 8; ++r) {
        const int q = wid * 8 + r;
        u16* p = Ss + q * 512 + ((lane ^ (q & 7)) << 3);
        short8 raw = *(short8*)p;
        float v[8];
#pragma unroll
        for (int i = 0; i < 8; ++i)
            v[i] = (msk[i] == 0) ? -1e9f : bf2f((u16)raw[i]);
        float mx = v[0];
#pragma unroll
        for (int i = 1; i < 8; ++i) mx = fmaxf(mx, v[i]);
#pragma unroll
        for (int o = 32; o; o >>= 1) mx = fmaxf(mx, __shfl_xor(mx, o));
        float e[8], sum = 0.f;
#pragma unroll
        for (int i = 0; i < 8; ++i) { e[i] = expf(v[i] - mx); sum += e[i]; }
#pragma unroll
        for (int o = 32; o; o >>= 1) sum += __shfl_xor(sum, o);
        float rr = 1.0f / sum;
        short8 o8;
#pragma unroll
        for (int i = 0; i < 8; ++i) o8[i] = (short)f2bf(e[i] * rr);
        *(short8*)p = o8;
    }
    __syncthreads();

    const int wr = wid >> 1, wc2 = wid & 1;
    f32x4 pacc[2] = {};
#pragma unroll
    for (int ks = 0; ks < 16; ++ks) {
        const int qrow = wr * 16 + lr;
        short8 pa = *(const short8*)(Ss + qrow * 512 + (((ks * 4 + lk) ^ (qrow & 7)) << 3));
        short8 vb[2];
#pragma unroll
        for (int n = 0; n < 2; ++n) {
            const int d = wc2 * 32 + n * 16 + lr;
            vb[n] = *(const short8*)(Vh + (long)d * 512 + ks * 32 + lk * 8);
        }
#pragma unroll
        for (int n = 0; n < 2; ++n)
            pacc[n] = __builtin_amdgcn_mfma_f32_16x16x32_bf16(pa, vb[n], pacc[n], 0, 0, 0);
    }
#pragma unroll
    for (int n = 0; n < 2; ++n) {
        const int d = wc2 * 32 + n * 16 + lr;
#pragma unroll
        for (int j = 0; j < 4; ++j) {
            const int q = wr * 16 + (lane >> 4) * 4 + j;
            const long F = ((long)bh << 15) + (long)(q0 + q) * 64 + d;
            const long r = F >> 10;
            const int  c = (int)(F & 1023);
            ctxB[(long)(c >> 6) * 262144L + r * 64 + (c & 63)] = f2bf(pacc[n][j]);
        }
    }
}

// ---------------------------------------------------------------------------
// wconv_blk: src fp32 [Z][K][N] -> dst bf16 BLOCKED [Z][K/64][planeN][64]
// ---------------------------------------------------------------------------
__global__ __launch_bounds__(256)
void wconv_blk(const float* __restrict__ src, u16* __restrict__ dst,
               int N, int planeN, int row_off, long src_z, long dst_z)
{
    __shared__ __align__(16) float t[64][65];
    const int z = blockIdx.z;
    const int k0 = blockIdx.x * 64, n0 = blockIdx.y * 64;
    const float* s = src + (long)z * src_z + (long)k0 * N + n0;
    const int tid = threadIdx.x;
#pragma unroll
    for (int i = 0; i < 4; ++i) {
        int ch = (i << 8) + tid;
        int r = ch >> 4, c4 = ch & 15;
        float4 v = *(const float4*)(s + (long)r * N + c4 * 4);
        t[r][c4 * 4 + 0] = v.x; t[r][c4 * 4 + 1] = v.y;
        t[r][c4 * 4 + 2] = v.z; t[r][c4 * 4 + 3] = v.w;
    }
    __syncthreads();
    u16* d = dst + (long)z * dst_z + (long)blockIdx.x * planeN * 64 + (long)(row_off + n0) * 64;
#pragma unroll
    for (int i = 0; i < 4; ++i) {
        int ch = (i << 8) + tid;
        int c = ch >> 4, k4 = ch & 15;
        ushort4 o;
        o.x = f2bf(t[k4 * 4 + 0][c]);
        o.y = f2bf(t[k4 * 4 + 1][c]);
        o.z = f2bf(t[k4 * 4 + 2][c]);
        o.w = f2bf(t[k4 * 4 + 3][c]);
        *(ushort4*)(d + (long)c * 64 + k4 * 4) = o;
    }
}

__global__ __launch_bounds__(256)
void bconcat_kernel(const float* __restrict__ bq, const float* __restrict__ bk,
                    const float* __restrict__ bv, float* __restrict__ out)
{
    int i = blockIdx.x * 256 + threadIdx.x;
    int l = i / 3072, n = i % 3072;
    float v = (n < 1024) ? bq[l * 1024 + n]
            : (n < 2048) ? bk[l * 1024 + n - 1024]
                         : bv[l * 1024 + n - 2048];
    out[i] = v;
}

__global__ __launch_bounds__(256)
void embed_kernel(const int* __restrict__ seq, const int* __restrict__ seg,
                  const float* __restrict__ tok, const float* __restrict__ sege,
                  float* __restrict__ x, u16* __restrict__ xbB)
{
    long i = ((long)blockIdx.x << 8) + threadIdx.x;
    int d2 = (int)(i & 511);
    long bl = i >> 9;
    int l = (int)(bl & 511);
    int t = seq[bl];
    int g = seg[bl];
    float div = powf(10000.f, -(float)(2 * d2) * (1.0f / 1024.f));
    float arg = (float)l * div;
    float sv = sinf(arg), cv = cosf(arg);
    long toff = (long)t * 1024 + 2 * d2;
    long goff = (long)g * 1024 + 2 * d2;
    float x0 = tok[toff]     + sv + sege[goff];
    float x1 = tok[toff + 1] + cv + sege[goff + 1];
    long xo = (bl << 10) + 2 * d2;
    x[xo] = x0; x[xo + 1] = x1;
    const int c = 2 * d2;
    u16* p = xbB + (long)(c >> 6) * 262144L + bl * 64 + (c & 63);
    p[0] = f2bf(x0); p[1] = f2bf(x1);
}

__global__ __launch_bounds__(256)
void vtrans_kernel(const u16* __restrict__ Vb, u16* __restrict__ vt)
{
    __shared__ __align__(16) u16 t[64][72];
    const int bh = blockIdx.y;
    const int l0 = blockIdx.x << 6;
    const u16* src = Vb + ((long)bh << 15) + (long)l0 * 64;
    const int tid = threadIdx.x;
#pragma unroll
    for (int i = 0; i < 2; ++i) {
        int ch = (i << 8) + tid;
        int r = ch >> 3, c8 = ch & 7;
        short8 v = *(const short8*)(src + (long)r * 64 + (c8 << 3));
#pragma unroll
        for (int j = 0; j < 8; ++j) t[r][(c8 << 3) + j] = (u16)v[j];
    }
    __syncthreads();
    u16* d = vt + ((long)bh << 15) + l0;
#pragma unroll
    for (int i = 0; i < 2; ++i) {
        int ch = (i << 8) + tid;
        int dd = ch >> 3, l8 = ch & 7;
        short8 o;
#pragma unroll
        for (int j = 0; j < 8; ++j) o[j] = (short)t[(l8 << 3) + j][dd];
        *(short8*)(d + (long)dd * 512 + (l8 << 3)) = o;
    }
}

__global__ __launch_bounds__(256)
void ln_kernel(const float* __restrict__ in, float* __restrict__ xout, u16* __restrict__ xbB)
{
    const int row = blockIdx.x;
    const int tid = threadIdx.x;
    const float4 v = ((const float4*)(in + (long)row * 1024))[tid];
    float s = v.x + v.y + v.z + v.w;
#pragma unroll
    for (int o = 32; o; o >>= 1) s += __shfl_down(s, o);
    __shared__ float red[8];
    const int wid = tid >> 6, lane = tid & 63;
    if (lane == 0) red[wid] = s;
    __syncthreads();
    const float mean = (red[0] + red[1] + red[2] + red[3]) * (1.0f / 1024.f);
    const float dx = v.x - mean, dy = v.y - mean, dz = v.z - mean, dw = v.w - mean;
    float q = dx * dx + dy * dy + dz * dz + dw * dw;
#pragma unroll
    for (int o = 32; o; o >>= 1) q += __shfl_down(q, o);
    if (lane == 0) red[4 + wid] = q;
    __syncthreads();
    const float var = (red[4] + red[5] + red[6] + red[7]) * (1.0f / 1024.f);
    const float inv = rsqrtf(var + 1e-5f);
    float4 o4;
    o4.x = dx * inv; o4.y = dy * inv; o4.z = dz * inv; o4.w = dw * inv;
    ((float4*)(xout + (long)row * 1024))[tid] = o4;
    ushort4 ob;
    ob.x = f2bf(o4.x); ob.y = f2bf(o4.y); ob.z = f2bf(o4.z); ob.w = f2bf(o4.w);
    *(ushort4*)(xbB + (long)(tid >> 4) * 262144L + (long)row * 64 + (tid & 15) * 4) = ob;
}

// ---------------------------------------------------------------------------
extern "C" void kernel_launch(void* const* d_in, const int* in_sizes, int n_in,
                              void* d_out, int out_size, void* d_ws, size_t ws_size,
                              hipStream_t stream)
{
    const int*   seqp = (const int*)d_in[0];
    const int*   segp = (const int*)d_in[1];
    const float* tok  = (const float*)d_in[2];
    const float* sege = (const float*)d_in[3];
    const float* Wq = (const float*)d_in[4];  const float* bq = (const float*)d_in[5];
    const float* Wk = (const float*)d_in[6];  const float* bk = (const float*)d_in[7];
    const float* Wv = (const float*)d_in[8];  const float* bv = (const float*)d_in[9];
    const float* Wo = (const float*)d_in[10]; const float* bo = (const float*)d_in[11];
    const float* W1 = (const float*)d_in[12]; const float* b1 = (const float*)d_in[13];
    const float* W2 = (const float*)d_in[14]; const float* b2 = (const float*)d_in[15];

    char* w = (char*)d_ws;
    auto take = [&](size_t bytes) -> void* {
        void* p = (void*)w; w += (bytes + 255) & ~(size_t)255; return p;
    };
    float* x    = (float*)take(4096UL * 1024 * 4);
    u16*   xbB  = (u16*)  take(4096UL * 1024 * 2);
    float* tmp  = (float*)take(4096UL * 1024 * 4);
    u16*   hbuf = (u16*)  take(4096UL * 4096 * 2);
    u16*   qkv3 = (u16*)  take(3UL * 4096 * 1024 * 2);
    u16*   ctxB = (u16*)  take(4096UL * 1024 * 2);
    u16*   vt   = (u16*)  take(128UL * 64 * 512 * 2);
    u16*   qkvwB= (u16*)  take(6UL * 3072 * 1024 * 2);
    u16*   woB  = (u16*)  take(6UL * 1024 * 1024 * 2);
    u16*   w1B  = (u16*)  take(6UL * 4096 * 1024 * 2);
    u16*   w2B  = (u16*)  take(6UL * 1024 * 4096 * 2);
    float* bqkv = (float*)take(6UL * 3072 * 4);

    u16* Qb = qkv3;
    u16* Kb = qkv3 + 4194304L;
    u16* Vb = qkv3 + 8388608L;

    bconcat_kernel<<<72, 256, 0, stream>>>(bq, bk, bv, bqkv);
    wconv_blk<<<dim3(16, 16, 6), 256, 0, stream>>>(Wq, qkvwB, 1024, 3072, 0,    1048576L, 3145728L);
    wconv_blk<<<dim3(16, 16, 6), 256, 0, stream>>>(Wk, qkvwB, 1024, 3072, 1024, 1048576L, 3145728L);
    wconv_blk<<<dim3(16, 16, 6), 256, 0, stream>>>(Wv, qkvwB, 1024, 3072, 2048, 1048576L, 3145728L);
    wconv_blk<<<dim3(16, 16, 6), 256, 0, stream>>>(Wo, woB,   1024, 1024, 0,    1048576L, 1048576L);
    wconv_blk<<<dim3(16, 64, 6), 256, 0, stream>>>(W1, w1B,   4096, 4096, 0,    4194304L, 4194304L);
    wconv_blk<<<dim3(64, 16, 6), 256, 0, stream>>>(W2, w2B,   1024, 1024, 0,    4194304L, 4194304L);

    embed_kernel<<<8192, 256, 0, stream>>>(seqp, segp, tok, sege, x, xbB);

    for (int l = 0; l < 6; ++l) {
        // fused QKV: 256^2 tile, blocked staging; routes col>>10 to Qb/Kb/Vb
        gemm256_blk<5><<<dim3(16, 12), 512, 0, stream>>>(
            xbB, qkvwB + (long)l * 3145728L, qkv3, bqkv + l * 3072,
            1024, 4096, 3072);

        vtrans_kernel<<<dim3(8, 128), 256, 0, stream>>>(Vb, vt);

        attn_kernel<<<dim3(8, 128), 512, 0, stream>>>(Qb, Kb, vt, seqp, ctxB);

        // Wo + bias + residual -> tmp f32 (128^2 blocked)
        gemm_k64<<<dim3(32, 8), 512, 0, stream>>>(
            ctxB, woB + (long)l * 1048576L, tmp, bo + l * 1024, x,
            1024, 4096, 1024);

        ln_kernel<<<4096, 256, 0, stream>>>(tmp, x, xbB);

        // FFN1 + GELU: 256^2 tile, blocked staging -> blocked hbuf
        gemm256_blk<6><<<dim3(16, 16), 512, 0, stream>>>(
            xbB, w1B + (long)l * 4194304L, hbuf, b1 + l * 4096,
            1024, 4096, 4096);

        // FFN2 + bias + residual -> tmp f32 (128^2 blocked)
        gemm_k64<<<dim3(32, 8), 512, 0, stream>>>(
            hbuf, w2B + (long)l * 4194304L, tmp, b2 + l * 1024, x,
            4096, 4096, 1024);

        ln_kernel<<<4096, 256, 0, stream>>>(tmp, (l == 5) ? (float*)d_out : x, xbB);
    }
}

// Round 17
// 1627.635 us; speedup vs baseline: 1.0829x; 1.0829x over previous
//
#include <hip/hip_runtime.h>
#include <cstdint>
#include <cstddef>

typedef unsigned short u16;
typedef __attribute__((ext_vector_type(8))) short short8;
typedef __attribute__((ext_vector_type(4))) float f32x4;

#define DEV __device__ __forceinline__

DEV float bf2f(u16 u) {
    union { float f; uint32_t i; } c; c.i = ((uint32_t)u) << 16; return c.f;
}
DEV u16 f2bf(float f) {
    union { float f; uint32_t i; } c; c.f = f;
    uint32_t r = c.i + 0x7FFF + ((c.i >> 16) & 1);
    return (u16)(r >> 16);
}

DEV void gload16(const void* g, void* l) {
    __builtin_amdgcn_global_load_lds(
        (const __attribute__((address_space(1))) void*)g,
        (__attribute__((address_space(3))) void*)l, 16, 0, 0);
}

template<int N> DEV void waitv() {
    if constexpr (N == 0)      asm volatile("s_waitcnt vmcnt(0)" ::: "memory");
    else if constexpr (N == 4) asm volatile("s_waitcnt vmcnt(4)" ::: "memory");
    else if constexpr (N == 8) asm volatile("s_waitcnt vmcnt(8)" ::: "memory");
    else                       asm volatile("s_waitcnt vmcnt(0)" ::: "memory");
}

// ---------------------------------------------------------------------------
// gemm256_blk (r15-proven, NO swizzle): 256x256 tile, BK=32, 8 waves, NBUF=3,
// 2-sub-phase schedule, blocked [K/64][rows][64] operands.
// EPI 5: bf16 = acc+bias routed by col>>10 (QKV).
// EPI 6: bf16 = gelu(acc+bias) -> BLOCKED [col>>6][row][col&63] (FFN1).
// ---------------------------------------------------------------------------
template<int EPI>
__global__ __launch_bounds__(512)
void gemm256_blk(const u16* __restrict__ Ablk, const u16* __restrict__ Bblk,
                 void* __restrict__ C, const float* __restrict__ bias,
                 int K, int Mtot, int Ntot)
{
    constexpr int THREADS = 512;
    constexpr int BM = 256, BN = 256, BK = 32;
    constexpr int MR = 8, NR = 4;
    __shared__ __align__(16) u16 As[3 * BM * BK];
    __shared__ __align__(16) u16 Bs[3 * BN * BK];

    const int tid = threadIdx.x, lane = tid & 63, wid = tid >> 6;
    const int wr = wid >> 2, wc = wid & 3;
    const int lr = lane & 15, lk = lane >> 4;
    const int m0 = blockIdx.x * BM, n0 = blockIdx.y * BN;
    const long planeA = (long)Mtot * 64, planeB = (long)Ntot * 64;

    f32x4 acc[MR][NR] = {};

    auto stageA = [&](int buf, int k0) {
        const long base = (long)(k0 >> 6) * planeA + (k0 & 32);
#pragma unroll
        for (int i = 0; i < 2; ++i) {
            int ch = i * THREADS + tid;
            int rp = ch >> 3, s = ch & 7, d = s ^ (rp & 7);
            const u16* g = Ablk + base + (long)(m0 + ((rp << 1) | (d & 1))) * 64 + ((d >> 1) << 3);
            gload16(g, (char*)As + (size_t)buf * (BM * BK * 2) + ch * 16);
        }
    };
    auto stageB = [&](int buf, int k0) {
        const long base = (long)(k0 >> 6) * planeB + (k0 & 32);
#pragma unroll
        for (int i = 0; i < 2; ++i) {
            int ch = i * THREADS + tid;
            int rp = ch >> 3, s = ch & 7, d = s ^ (rp & 7);
            const u16* g = Bblk + base + (long)(n0 + ((rp << 1) | (d & 1))) * 64 + ((d >> 1) << 3);
            gload16(g, (char*)Bs + (size_t)buf * (BN * BK * 2) + ch * 16);
        }
    };
    auto lds_off = [&](int row) -> int {
        int rp = row >> 1;
        int s  = ((lk << 1) | (row & 1)) ^ (rp & 7);
        return rp * 64 + s * 8;
    };

    const int nt = K >> 5;

    stageA(0, 0); stageB(0, 0);
    if (nt > 1) { stageA(1, BK); stageB(1, BK); }
    if (nt > 1) waitv<4>(); else waitv<0>();
    __builtin_amdgcn_s_barrier();

    for (int k = 0; k < nt; ++k) {
        const int cur = k % 3;
        const int nxt = (k + 2) % 3;
        const u16* Ac = As + (size_t)cur * (BM * BK);
        const u16* Bc = Bs + (size_t)cur * (BN * BK);
        short8 af[MR], bf[NR];

#pragma unroll
        for (int n = 0; n < NR; ++n)
            bf[n] = *(const short8*)(Bc + lds_off(wc * 64 + n * 16 + lr));
#pragma unroll
        for (int m = 0; m < 4; ++m)
            af[m] = *(const short8*)(Ac + lds_off(wr * 128 + m * 16 + lr));
        if (k + 2 < nt) stageA(nxt, (k + 2) * BK);
        asm volatile("s_waitcnt lgkmcnt(0)" ::: "memory");
        __builtin_amdgcn_s_setprio(1);
#pragma unroll
        for (int m = 0; m < 4; ++m)
#pragma unroll
            for (int n = 0; n < NR; ++n)
                acc[m][n] = __builtin_amdgcn_mfma_f32_16x16x32_bf16(af[m], bf[n], acc[m][n], 0, 0, 0);
        __builtin_amdgcn_s_setprio(0);

#pragma unroll
        for (int m = 4; m < 8; ++m)
            af[m] = *(const short8*)(Ac + lds_off(wr * 128 + m * 16 + lr));
        if (k + 2 < nt) stageB(nxt, (k + 2) * BK);
        asm volatile("s_waitcnt lgkmcnt(0)" ::: "memory");
        __builtin_amdgcn_s_setprio(1);
#pragma unroll
        for (int m = 4; m < 8; ++m)
#pragma unroll
            for (int n = 0; n < NR; ++n)
                acc[m][n] = __builtin_amdgcn_mfma_f32_16x16x32_bf16(af[m], bf[n], acc[m][n], 0, 0, 0);
        __builtin_amdgcn_s_setprio(0);

        if (k + 1 < nt) {
            if (k + 2 < nt) waitv<4>(); else waitv<0>();
            __builtin_amdgcn_s_barrier();
        }
    }

#pragma unroll
    for (int m = 0; m < MR; ++m) {
        const int rowb = m0 + wr * 128 + m * 16 + (lane >> 4) * 4;
#pragma unroll
        for (int n = 0; n < NR; ++n) {
            const int col = n0 + wc * 64 + n * 16 + lr;
            const float bv = bias[col];
#pragma unroll
            for (int j = 0; j < 4; ++j) {
                float v = acc[m][n][j];
                if (EPI == 6) {
                    float t = v + bv;
                    ((u16*)C)[(long)(col >> 6) * 262144L + (long)(rowb + j) * 64 + (col & 63)]
                        = f2bf(0.5f * t * (1.0f + erff(t * 0.70710678118654752f)));
                } else {  // EPI 5: QKV routing
                    const long qidx = (long)(col >> 10) * 4194304L
                                    + (long)(rowb + j) * 1024 + (col & 1023);
                    ((u16*)C)[qidx] = f2bf(v + bv);
                }
            }
        }
    }
}

// ---------------------------------------------------------------------------
// gemm_k64 (r15-proven, NO swizzle): 128x128, BK=64, blocked A/B, N=1024.
// EPI: f32 = acc + bias[col] + resid[row*1024+col].
// ---------------------------------------------------------------------------
__global__ __launch_bounds__(512)
void gemm_k64(const u16* __restrict__ Ablk, const u16* __restrict__ Bblk,
              float* __restrict__ C, const float* __restrict__ bias,
              const float* __restrict__ resid, int K, int Mtot, int Ntot)
{
    constexpr int THREADS = 512;
    constexpr int BM = 128, BN = 128;
    constexpr int MR = 4, NR = 2;
    __shared__ __align__(16) u16 As[3 * BM * 64];
    __shared__ __align__(16) u16 Bs[3 * BN * 64];

    const int tid = threadIdx.x, lane = tid & 63, wid = tid >> 6;
    const int wr = wid >> 2, wc = wid & 3;
    const int lr = lane & 15, lk = lane >> 4;
    const int m0 = blockIdx.x * BM, n0 = blockIdx.y * BN;
    const long planeA = (long)Mtot * 64, planeB = (long)Ntot * 64;

    f32x4 acc[MR][NR] = {};

    auto stageA = [&](int buf, int k0) {
#pragma unroll
        for (int i = 0; i < 2; ++i) {
            int ch = i * THREADS + tid;
            int row = ch >> 3, s = ch & 7, d = s ^ (row & 7);
            const u16* g = Ablk + (long)(k0 >> 6) * planeA + (long)(m0 + row) * 64 + d * 8;
            gload16(g, (char*)As + (size_t)buf * (BM * 128) + ch * 16);
        }
    };
    auto stageB = [&](int buf, int k0) {
#pragma unroll
        for (int i = 0; i < 2; ++i) {
            int ch = i * THREADS + tid;
            int row = ch >> 3, s = ch & 7, d = s ^ (row & 7);
            const u16* g = Bblk + (long)(k0 >> 6) * planeB + (long)(n0 + row) * 64 + d * 8;
            gload16(g, (char*)Bs + (size_t)buf * (BN * 128) + ch * 16);
        }
    };
    auto lds_off = [&](int row, int ks) -> int {
        return row * 64 + ((ks ^ (row & 7)) << 3);
    };

    const int nt = K >> 6;

    stageA(0, 0); stageB(0, 0);
    if (nt > 1) { stageA(1, 64); stageB(1, 64); }
    if (nt > 2) { stageA(2, 128); stageB(2, 128); }
    if (nt > 2)      waitv<8>();
    else if (nt > 1) waitv<4>();
    else             waitv<0>();
    __builtin_amdgcn_s_barrier();

    for (int k = 0; k < nt; ++k) {
        const int cur = k % 3;
        const u16* Ac = As + (size_t)cur * (BM * 64);
        const u16* Bc = Bs + (size_t)cur * (BN * 64);
        short8 af[2][MR], bf[2][NR];
#pragma unroll
        for (int h = 0; h < 2; ++h) {
#pragma unroll
            for (int m = 0; m < MR; ++m)
                af[h][m] = *(const short8*)(Ac + lds_off(wr * 64 + m * 16 + lr, h * 4 + lk));
#pragma unroll
            for (int n = 0; n < NR; ++n)
                bf[h][n] = *(const short8*)(Bc + lds_off(wc * 32 + n * 16 + lr, h * 4 + lk));
        }

        asm volatile("s_waitcnt lgkmcnt(0)" ::: "memory");
        __builtin_amdgcn_s_barrier();

        if (k + 3 < nt) { stageA(cur, (k + 3) * 64); stageB(cur, (k + 3) * 64); }

        __builtin_amdgcn_s_setprio(1);
#pragma unroll
        for (int h = 0; h < 2; ++h)
#pragma unroll
            for (int m = 0; m < MR; ++m)
#pragma unroll
                for (int n = 0; n < NR; ++n)
                    acc[m][n] = __builtin_amdgcn_mfma_f32_16x16x32_bf16(af[h][m], bf[h][n], acc[m][n], 0, 0, 0);
        __builtin_amdgcn_s_setprio(0);

        if (k + 1 < nt) {
            if (k + 4 <= nt)      waitv<8>();
            else if (k + 3 == nt) waitv<4>();
            else                  waitv<0>();
            __builtin_amdgcn_s_barrier();
        }
    }

#pragma unroll
    for (int m = 0; m < MR; ++m) {
        const int rowb = m0 + wr * 64 + m * 16 + (lane >> 4) * 4;
#pragma unroll
        for (int n = 0; n < NR; ++n) {
            const int col = n0 + wc * 32 + n * 16 + lr;
            const float bv = bias[col];
#pragma unroll
            for (int j = 0; j < 4; ++j) {
                const long idx = (long)(rowb + j) * 1024 + col;
                C[idx] = acc[m][n][j] + bv + resid[idx];
            }
        }
    }
}

// ---------------------------------------------------------------------------
// Fused attention (r12-proven) + XCD swizzle (kept: correct orientation —
// each XCD owns 16 consecutive (b,h) groups, K/V panels localized in its L2).
// ---------------------------------------------------------------------------
__global__ __launch_bounds__(512)
void attn_kernel(const u16* __restrict__ Qb, const u16* __restrict__ Kb,
                 const u16* __restrict__ vt, const int* __restrict__ seq,
                 u16* __restrict__ ctxB)
{
    __shared__ __align__(16) u16 Ss[64 * 512];
    // bijective remap: XCD c gets lin%8==c -> logical L in [c*128,(c+1)*128)
    const int lin = blockIdx.y * 8 + blockIdx.x;
    const int L   = (lin & 7) * 128 + (lin >> 3);
    const int bh  = L >> 3;
    const int q0  = (L & 7) << 6;
    const int tid = threadIdx.x, lane = tid & 63, wid = tid >> 6;
    const int b  = bh >> 4;
    const u16* Qh = Qb + ((long)bh << 15) + (long)q0 * 64;
    const u16* Kh = Kb + ((long)bh << 15);
    const u16* Vh = vt + ((long)bh << 15);
    const int lr = lane & 15, lk = lane >> 4;

    f32x4 sacc[4][4] = {};
    {
        short8 af[4], bf[4];
#pragma unroll
        for (int s = 0; s < 2; ++s) {
#pragma unroll
            for (int m = 0; m < 4; ++m)
                af[m] = *(const short8*)(Qh + (long)(m * 16 + lr) * 64 + s * 32 + lk * 8);
#pragma unroll
            for (int n = 0; n < 4; ++n)
                bf[n] = *(const short8*)(Kh + (long)(wid * 64 + n * 16 + lr) * 64 + s * 32 + lk * 8);
#pragma unroll
            for (int m = 0; m < 4; ++m)
#pragma unroll
                for (int n = 0; n < 4; ++n)
                    sacc[m][n] = __builtin_amdgcn_mfma_f32_16x16x32_bf16(af[m], bf[n], sacc[m][n], 0, 0, 0);
        }
    }
#pragma unroll
    for (int m = 0; m < 4; ++m) {
#pragma unroll
        for (int n = 0; n < 4; ++n) {
            const int k = wid * 64 + n * 16 + lr;
#pragma unroll
            for (int j = 0; j < 4; ++j) {
                const int q = m * 16 + (lane >> 4) * 4 + j;
                const int col = (((k >> 3) ^ (q & 7)) << 3) | (k & 7);
                Ss[q * 512 + col] = f2bf(sacc[m][n][j] * 0.125f);
            }
        }
    }
    __syncthreads();

    const int* sq = seq + (b << 9) + (lane << 3);
    int msk[8];
#pragma unroll
    for (int i = 0; i < 8; ++i) msk[i] = sq[i];
#pragma unroll
    for (int r = 0; r < 8; ++r) {
        const int q = wid * 8 + r;
        u16* p = Ss + q * 512 + ((lane ^ (q & 7)) << 3);
        short8 raw = *(short8*)p;
        float v[8];
#pragma unroll
        for (int i = 0; i < 8; ++i)
            v[i] = (msk[i] == 0) ? -1e9f : bf2f((u16)raw[i]);
        float mx = v[0];
#pragma unroll
        for (int i = 1; i < 8; ++i) mx = fmaxf(mx, v[i]);
#pragma unroll
        for (int o = 32; o; o >>= 1) mx = fmaxf(mx, __shfl_xor(mx, o));
        float e[8], sum = 0.f;
#pragma unroll
        for (int i = 0; i < 8; ++i) { e[i] = expf(v[i] - mx); sum += e[i]; }
#pragma unroll
        for (int o = 32; o; o >>= 1) sum += __shfl_xor(sum, o);
        float rr = 1.0f / sum;
        short8 o8;
#pragma unroll
        for (int i = 0; i < 8; ++i) o8[i] = (short)f2bf(e[i] * rr);
        *(short8*)p = o8;
    }
    __syncthreads();

    const int wr = wid >> 1, wc2 = wid & 1;
    f32x4 pacc[2] = {};
#pragma unroll
    for (int ks = 0; ks < 16; ++ks) {
        const int qrow = wr * 16 + lr;
        short8 pa = *(const short8*)(Ss + qrow * 512 + (((ks * 4 + lk) ^ (qrow & 7)) << 3));
        short8 vb[2];
#pragma unroll
        for (int n = 0; n < 2; ++n) {
            const int d = wc2 * 32 + n * 16 + lr;
            vb[n] = *(const short8*)(Vh + (long)d * 512 + ks * 32 + lk * 8);
        }
#pragma unroll
        for (int n = 0; n < 2; ++n)
            pacc[n] = __builtin_amdgcn_mfma_f32_16x16x32_bf16(pa, vb[n], pacc[n], 0, 0, 0);
    }
#pragma unroll
    for (int n = 0; n < 2; ++n) {
        const int d = wc2 * 32 + n * 16 + lr;
#pragma unroll
        for (int j = 0; j < 4; ++j) {
            const int q = wr * 16 + (lane >> 4) * 4 + j;
            const long F = ((long)bh << 15) + (long)(q0 + q) * 64 + d;
            const long r = F >> 10;
            const int  c = (int)(F & 1023);
            ctxB[(long)(c >> 6) * 262144L + r * 64 + (c & 63)] = f2bf(pacc[n][j]);
        }
    }
}

// ---------------------------------------------------------------------------
// wconv_blk: src fp32 [Z][K][N] -> dst bf16 BLOCKED [Z][K/64][planeN][64]
// ---------------------------------------------------------------------------
__global__ __launch_bounds__(256)
void wconv_blk(const float* __restrict__ src, u16* __restrict__ dst,
               int N, int planeN, int row_off, long src_z, long dst_z)
{
    __shared__ __align__(16) float t[64][65];
    const int z = blockIdx.z;
    const int k0 = blockIdx.x * 64, n0 = blockIdx.y * 64;
    const float* s = src + (long)z * src_z + (long)k0 * N + n0;
    const int tid = threadIdx.x;
#pragma unroll
    for (int i = 0; i < 4; ++i) {
        int ch = (i << 8) + tid;
        int r = ch >> 4, c4 = ch & 15;
        float4 v = *(const float4*)(s + (long)r * N + c4 * 4);
        t[r][c4 * 4 + 0] = v.x; t[r][c4 * 4 + 1] = v.y;
        t[r][c4 * 4 + 2] = v.z; t[r][c4 * 4 + 3] = v.w;
    }
    __syncthreads();
    u16* d = dst + (long)z * dst_z + (long)blockIdx.x * planeN * 64 + (long)(row_off + n0) * 64;
#pragma unroll
    for (int i = 0; i < 4; ++i) {
        int ch = (i << 8) + tid;
        int c = ch >> 4, k4 = ch & 15;
        ushort4 o;
        o.x = f2bf(t[k4 * 4 + 0][c]);
        o.y = f2bf(t[k4 * 4 + 1][c]);
        o.z = f2bf(t[k4 * 4 + 2][c]);
        o.w = f2bf(t[k4 * 4 + 3][c]);
        *(ushort4*)(d + (long)c * 64 + k4 * 4) = o;
    }
}

__global__ __launch_bounds__(256)
void bconcat_kernel(const float* __restrict__ bq, const float* __restrict__ bk,
                    const float* __restrict__ bv, float* __restrict__ out)
{
    int i = blockIdx.x * 256 + threadIdx.x;
    int l = i / 3072, n = i % 3072;
    float v = (n < 1024) ? bq[l * 1024 + n]
            : (n < 2048) ? bk[l * 1024 + n - 1024]
                         : bv[l * 1024 + n - 2048];
    out[i] = v;
}

__global__ __launch_bounds__(256)
void embed_kernel(const int* __restrict__ seq, const int* __restrict__ seg,
                  const float* __restrict__ tok, const float* __restrict__ sege,
                  float* __restrict__ x, u16* __restrict__ xbB)
{
    long i = ((long)blockIdx.x << 8) + threadIdx.x;
    int d2 = (int)(i & 511);
    long bl = i >> 9;
    int l = (int)(bl & 511);
    int t = seq[bl];
    int g = seg[bl];
    float div = powf(10000.f, -(float)(2 * d2) * (1.0f / 1024.f));
    float arg = (float)l * div;
    float sv = sinf(arg), cv = cosf(arg);
    long toff = (long)t * 1024 + 2 * d2;
    long goff = (long)g * 1024 + 2 * d2;
    float x0 = tok[toff]     + sv + sege[goff];
    float x1 = tok[toff + 1] + cv + sege[goff + 1];
    long xo = (bl << 10) + 2 * d2;
    x[xo] = x0; x[xo + 1] = x1;
    const int c = 2 * d2;
    u16* p = xbB + (long)(c >> 6) * 262144L + bl * 64 + (c & 63);
    p[0] = f2bf(x0); p[1] = f2bf(x1);
}

__global__ __launch_bounds__(256)
void vtrans_kernel(const u16* __restrict__ Vb, u16* __restrict__ vt)
{
    __shared__ __align__(16) u16 t[64][72];
    const int bh = blockIdx.y;
    const int l0 = blockIdx.x << 6;
    const u16* src = Vb + ((long)bh << 15) + (long)l0 * 64;
    const int tid = threadIdx.x;
#pragma unroll
    for (int i = 0; i < 2; ++i) {
        int ch = (i << 8) + tid;
        int r = ch >> 3, c8 = ch & 7;
        short8 v = *(const short8*)(src + (long)r * 64 + (c8 << 3));
#pragma unroll
        for (int j = 0; j < 8; ++j) t[r][(c8 << 3) + j] = (u16)v[j];
    }
    __syncthreads();
    u16* d = vt + ((long)bh << 15) + l0;
#pragma unroll
    for (int i = 0; i < 2; ++i) {
        int ch = (i << 8) + tid;
        int dd = ch >> 3, l8 = ch & 7;
        short8 o;
#pragma unroll
        for (int j = 0; j < 8; ++j) o[j] = (short)t[(l8 << 3) + j][dd];
        *(short8*)(d + (long)dd * 512 + (l8 << 3)) = o;
    }
}

__global__ __launch_bounds__(256)
void ln_kernel(const float* __restrict__ in, float* __restrict__ xout, u16* __restrict__ xbB)
{
    const int row = blockIdx.x;
    const int tid = threadIdx.x;
    const float4 v = ((const float4*)(in + (long)row * 1024))[tid];
    float s = v.x + v.y + v.z + v.w;
#pragma unroll
    for (int o = 32; o; o >>= 1) s += __shfl_down(s, o);
    __shared__ float red[8];
    const int wid = tid >> 6, lane = tid & 63;
    if (lane == 0) red[wid] = s;
    __syncthreads();
    const float mean = (red[0] + red[1] + red[2] + red[3]) * (1.0f / 1024.f);
    const float dx = v.x - mean, dy = v.y - mean, dz = v.z - mean, dw = v.w - mean;
    float q = dx * dx + dy * dy + dz * dz + dw * dw;
#pragma unroll
    for (int o = 32; o; o >>= 1) q += __shfl_down(q, o);
    if (lane == 0) red[4 + wid] = q;
    __syncthreads();
    const float var = (red[4] + red[5] + red[6] + red[7]) * (1.0f / 1024.f);
    const float inv = rsqrtf(var + 1e-5f);
    float4 o4;
    o4.x = dx * inv; o4.y = dy * inv; o4.z = dz * inv; o4.w = dw * inv;
    ((float4*)(xout + (long)row * 1024))[tid] = o4;
    ushort4 ob;
    ob.x = f2bf(o4.x); ob.y = f2bf(o4.y); ob.z = f2bf(o4.z); ob.w = f2bf(o4.w);
    *(ushort4*)(xbB + (long)(tid >> 4) * 262144L + (long)row * 64 + (tid & 15) * 4) = ob;
}

// ---------------------------------------------------------------------------
extern "C" void kernel_launch(void* const* d_in, const int* in_sizes, int n_in,
                              void* d_out, int out_size, void* d_ws, size_t ws_size,
                              hipStream_t stream)
{
    const int*   seqp = (const int*)d_in[0];
    const int*   segp = (const int*)d_in[1];
    const float* tok  = (const float*)d_in[2];
    const float* sege = (const float*)d_in[3];
    const float* Wq = (const float*)d_in[4];  const float* bq = (const float*)d_in[5];
    const float* Wk = (const float*)d_in[6];  const float* bk = (const float*)d_in[7];
    const float* Wv = (const float*)d_in[8];  const float* bv = (const float*)d_in[9];
    const float* Wo = (const float*)d_in[10]; const float* bo = (const float*)d_in[11];
    const float* W1 = (const float*)d_in[12]; const float* b1 = (const float*)d_in[13];
    const float* W2 = (const float*)d_in[14]; const float* b2 = (const float*)d_in[15];

    char* w = (char*)d_ws;
    auto take = [&](size_t bytes) -> void* {
        void* p = (void*)w; w += (bytes + 255) & ~(size_t)255; return p;
    };
    float* x    = (float*)take(4096UL * 1024 * 4);
    u16*   xbB  = (u16*)  take(4096UL * 1024 * 2);
    float* tmp  = (float*)take(4096UL * 1024 * 4);
    u16*   hbuf = (u16*)  take(4096UL * 4096 * 2);
    u16*   qkv3 = (u16*)  take(3UL * 4096 * 1024 * 2);
    u16*   ctxB = (u16*)  take(4096UL * 1024 * 2);
    u16*   vt   = (u16*)  take(128UL * 64 * 512 * 2);
    u16*   qkvwB= (u16*)  take(6UL * 3072 * 1024 * 2);
    u16*   woB  = (u16*)  take(6UL * 1024 * 1024 * 2);
    u16*   w1B  = (u16*)  take(6UL * 4096 * 1024 * 2);
    u16*   w2B  = (u16*)  take(6UL * 1024 * 4096 * 2);
    float* bqkv = (float*)take(6UL * 3072 * 4);

    u16* Qb = qkv3;
    u16* Kb = qkv3 + 4194304L;
    u16* Vb = qkv3 + 8388608L;

    bconcat_kernel<<<72, 256, 0, stream>>>(bq, bk, bv, bqkv);
    wconv_blk<<<dim3(16, 16, 6), 256, 0, stream>>>(Wq, qkvwB, 1024, 3072, 0,    1048576L, 3145728L);
    wconv_blk<<<dim3(16, 16, 6), 256, 0, stream>>>(Wk, qkvwB, 1024, 3072, 1024, 1048576L, 3145728L);
    wconv_blk<<<dim3(16, 16, 6), 256, 0, stream>>>(Wv, qkvwB, 1024, 3072, 2048, 1048576L, 3145728L);
    wconv_blk<<<dim3(16, 16, 6), 256, 0, stream>>>(Wo, woB,   1024, 1024, 0,    1048576L, 1048576L);
    wconv_blk<<<dim3(16, 64, 6), 256, 0, stream>>>(W1, w1B,   4096, 4096, 0,    4194304L, 4194304L);
    wconv_blk<<<dim3(64, 16, 6), 256, 0, stream>>>(W2, w2B,   1024, 1024, 0,    4194304L, 4194304L);

    embed_kernel<<<8192, 256, 0, stream>>>(seqp, segp, tok, sege, x, xbB);

    for (int l = 0; l < 6; ++l) {
        // fused QKV: 256^2 tile, blocked staging; routes col>>10 to Qb/Kb/Vb
        gemm256_blk<5><<<dim3(16, 12), 512, 0, stream>>>(
            xbB, qkvwB + (long)l * 3145728L, qkv3, bqkv + l * 3072,
            1024, 4096, 3072);

        vtrans_kernel<<<dim3(8, 128), 256, 0, stream>>>(Vb, vt);

        attn_kernel<<<dim3(8, 128), 512, 0, stream>>>(Qb, Kb, vt, seqp, ctxB);

        // Wo + bias + residual -> tmp f32 (128^2 blocked)
        gemm_k64<<<dim3(32, 8), 512, 0, stream>>>(
            ctxB, woB + (long)l * 1048576L, tmp, bo + l * 1024, x,
            1024, 4096, 1024);

        ln_kernel<<<4096, 256, 0, stream>>>(tmp, x, xbB);

        // FFN1 + GELU: 256^2 tile, blocked staging -> blocked hbuf
        gemm256_blk<6><<<dim3(16, 16), 512, 0, stream>>>(
            xbB, w1B + (long)l * 4194304L, hbuf, b1 + l * 4096,
            1024, 4096, 4096);

        // FFN2 + bias + residual -> tmp f32 (128^2 blocked)
        gemm_k64<<<dim3(32, 8), 512, 0, stream>>>(
            hbuf, w2B + (long)l * 4194304L, tmp, b2 + l * 1024, x,
            4096, 4096, 1024);

        ln_kernel<<<4096, 256, 0, stream>>>(tmp, (l == 5) ? (float*)d_out : x, xbB);
    }
}